// Round 1
// baseline (72.099 us; speedup 1.0000x reference)
//
#include <hip/hip_runtime.h>

#define NB 32
#define RR 128
#define FF 128

// Transpose x2[n][j][f] -> x2t[n][f][j] so the main kernel's inner f-loop
// reads lane-consecutive j (coalesced float4). 32x32 LDS tiles, +1 pad.
__global__ __launch_bounds__(256) void transpose_x2(const float* __restrict__ x2,
                                                    float* __restrict__ x2t) {
  __shared__ float tile[32][33];
  const int n = blockIdx.z;
  const int jt = blockIdx.x * 32;
  const int ft = blockIdx.y * 32;
  const int tx = threadIdx.x;  // 0..31
  const int ty = threadIdx.y;  // 0..7
  const float* src = x2 + (size_t)n * RR * FF;
  float* dst = x2t + (size_t)n * RR * FF;
#pragma unroll
  for (int k = 0; k < 32; k += 8)
    tile[ty + k][tx] = src[(jt + ty + k) * FF + ft + tx];
  __syncthreads();
#pragma unroll
  for (int k = 0; k < 32; k += 8)
    dst[(ft + ty + k) * RR + jt + tx] = tile[tx][ty + k];
}

// One block = (n, 4 consecutive i-rows). 128 threads = 32 j-quads (tx) x 4 rows (ty).
// Each thread owns 4 j's of one row: full 128-f dot, then exp + row softmax via
// half-wave shuffles (row's 128 values = 32 lanes x 4 regs, lanes 0..31 or 32..63).
template <bool TRANSPOSED>
__global__ __launch_bounds__(128) void gauss_softmax(const float* __restrict__ x1,
                                                     const float* __restrict__ xb,
                                                     const float* __restrict__ sigma,
                                                     const float* __restrict__ mean,
                                                     float* __restrict__ out) {
  const int bid = blockIdx.x;
  const int n = bid >> 5;          // 32 i-tiles per n
  const int i0 = (bid & 31) << 2;  // 4 rows per block
  const int tid = threadIdx.x;
  const int tx = tid & 31;
  const int ty = tid >> 5;  // 0..3 (row within tile)
  __shared__ float sh_a[4 * FF];

  const float mval = mean[0];
  const float sg = sigma[0];
  const float cneg = -1.0f / (2.0f * sg * sg);

  // Stage 4 x1 rows into LDS with mean pre-folded (512 floats, one float4/thread).
  {
    const float4 v = ((const float4*)(x1 + (size_t)(n * RR + i0) * FF))[tid];
    ((float4*)sh_a)[tid] = make_float4(v.x - mval, v.y - mval, v.z - mval, v.w - mval);
  }
  __syncthreads();

  float acc0 = 0.f, acc1 = 0.f, acc2 = 0.f, acc3 = 0.f;
  const float* base = xb + (size_t)n * RR * FF;
  const int j0 = tx << 2;
  const float* arow = sh_a + ty * FF;

#pragma unroll 8
  for (int f = 0; f < FF; ++f) {
    float4 b;
    if (TRANSPOSED) {
      b = *(const float4*)(base + f * RR + j0);  // lane-consecutive: coalesced
    } else {
      b.x = base[(j0 + 0) * FF + f];
      b.y = base[(j0 + 1) * FF + f];
      b.z = base[(j0 + 2) * FF + f];
      b.w = base[(j0 + 3) * FF + f];
    }
    const float a = arow[f];
    float d;
    d = a - b.x; acc0 = fmaf(d, d, acc0);
    d = a - b.y; acc1 = fmaf(d, d, acc1);
    d = a - b.z; acc2 = fmaf(d, d, acc2);
    d = a - b.w; acc3 = fmaf(d, d, acc3);
  }

  // kernel_value = exp(-ds / (2*sigma^2))
  const float k0 = __expf(acc0 * cneg);
  const float k1 = __expf(acc1 * cneg);
  const float k2 = __expf(acc2 * cneg);
  const float k3 = __expf(acc3 * cneg);

  // Row softmax over j (128 values in 32 lanes x 4 regs). xor masks <32 stay
  // inside each 32-lane half of the wave64, i.e. inside one row.
  float mx = fmaxf(fmaxf(k0, k1), fmaxf(k2, k3));
#pragma unroll
  for (int off = 16; off >= 1; off >>= 1) mx = fmaxf(mx, __shfl_xor(mx, off, 64));
  const float e0 = __expf(k0 - mx);
  const float e1 = __expf(k1 - mx);
  const float e2 = __expf(k2 - mx);
  const float e3 = __expf(k3 - mx);
  float ssum = e0 + e1 + e2 + e3;
#pragma unroll
  for (int off = 16; off >= 1; off >>= 1) ssum += __shfl_xor(ssum, off, 64);
  const float r = 1.0f / ssum;

  *(float4*)(out + (size_t)(n * RR + i0 + ty) * RR + j0) =
      make_float4(e0 * r, e1 * r, e2 * r, e3 * r);
}

extern "C" void kernel_launch(void* const* d_in, const int* in_sizes, int n_in,
                              void* d_out, int out_size, void* d_ws, size_t ws_size,
                              hipStream_t stream) {
  const float* x1 = (const float*)d_in[0];
  const float* x2 = (const float*)d_in[1];
  const float* sigma = (const float*)d_in[2];
  const float* mean = (const float*)d_in[3];
  float* out = (float*)d_out;

  const size_t needed = (size_t)NB * RR * FF * sizeof(float);
  if (ws_size >= needed) {
    float* x2t = (float*)d_ws;
    transpose_x2<<<dim3(4, 4, NB), dim3(32, 8), 0, stream>>>(x2, x2t);
    gauss_softmax<true><<<dim3(NB * 32), dim3(128), 0, stream>>>(x1, x2t, sigma, mean, out);
  } else {
    // Fallback: read x2 untransposed (uncoalesced but correct; L2-resident).
    gauss_softmax<false><<<dim3(NB * 32), dim3(128), 0, stream>>>(x1, x2, sigma, mean, out);
  }
}

// Round 2
// 69.071 us; speedup vs baseline: 1.0438x; 1.0438x over previous
//
#include <hip/hip_runtime.h>

#define NB 32
#define RR 128
#define FF 128
#define FT 32   // f-tile width
#define SB 132  // LDS stride for transposed b-tile: 132*4B = 528B, 16B-aligned rows

// Fully fused: per block = (n, 8 consecutive i-rows). 256 threads = 32 j-quads
// (tx) x 8 rows (ty). Iterate f in tiles of 32: stage x2[n][:, ft:ft+32]
// coalesced global -> LDS transposed [f][j], then accumulate (a-b)^2 with
// lane-consecutive ds_read_b128. Softmax per row via half-wave shuffles.
// No workspace use: avoids the harness's 268 MB d_ws poison fill in the
// timed path (R1: fillBufferAligned at 43 us dominated the profile).
__global__ __launch_bounds__(256) void gauss_fused(const float* __restrict__ x1,
                                                   const float* __restrict__ x2,
                                                   const float* __restrict__ sigma,
                                                   const float* __restrict__ mean,
                                                   float* __restrict__ out) {
  __shared__ __align__(16) float sh_b[FT * SB];  // 16.5 KB, transposed [f][j]
  __shared__ __align__(16) float sh_a[8 * FF];   // 4 KB, 8 x1 rows, mean folded

  const int bid = blockIdx.x;
  const int n = bid >> 4;          // 16 i-octets per n
  const int i0 = (bid & 15) << 3;  // 8 rows per block
  const int tid = threadIdx.x;
  const int tx = tid & 31;   // j-quad
  const int ty = tid >> 5;   // row 0..7

  const float mval = mean[0];
  const float sg = sigma[0];
  const float cneg = -1.0f / (2.0f * sg * sg);

  // Stage 8 x1 rows (1024 floats) with mean pre-folded: one float4/thread.
  {
    const float4 v = ((const float4*)(x1 + (size_t)(n * RR + i0) * FF))[tid];
    ((float4*)sh_a)[tid] = make_float4(v.x - mval, v.y - mval, v.z - mval, v.w - mval);
  }

  const float* __restrict__ x2base = x2 + (size_t)n * RR * FF;
  const int jj = tid >> 3;        // 0..31: row within 32-row staging chunk
  const int fo = (tid & 7) << 2;  // 0,4,...,28: f-offset quad within tile

  float acc0 = 0.f, acc1 = 0.f, acc2 = 0.f, acc3 = 0.f;
  const int j0 = tx << 2;
  const float* __restrict__ arow = sh_a + ty * FF;

  for (int t = 0; t < FF / FT; ++t) {
    const int ftw = t * FT;
    __syncthreads();  // prior tile's reads done before overwriting sh_b
    // Stage 128 j x 32 f = 16 KB, transposed. Each 8-lane group reads a
    // contiguous 128 B row segment (coalesced). Scalar LDS writes, 4-way
    // bank conflict (~1.58x) - writes are 1/4 of LDS traffic, acceptable.
#pragma unroll
    for (int p = 0; p < 4; ++p) {
      const int j = jj + p * 32;
      const float4 v = *(const float4*)(x2base + (size_t)j * FF + ftw + fo);
      sh_b[(fo + 0) * SB + j] = v.x;
      sh_b[(fo + 1) * SB + j] = v.y;
      sh_b[(fo + 2) * SB + j] = v.z;
      sh_b[(fo + 3) * SB + j] = v.w;
    }
    __syncthreads();

#pragma unroll
    for (int f = 0; f < FT; ++f) {
      const float4 b = *(const float4*)(sh_b + f * SB + j0);  // lane-consecutive b128
      const float a = arow[ftw + f];                          // broadcast
      float d;
      d = a - b.x; acc0 = fmaf(d, d, acc0);
      d = a - b.y; acc1 = fmaf(d, d, acc1);
      d = a - b.z; acc2 = fmaf(d, d, acc2);
      d = a - b.w; acc3 = fmaf(d, d, acc3);
    }
  }

  // kernel_value = exp(-ds / (2 sigma^2)), then softmax over j (row = 32
  // lanes x 4 regs; xor offsets <32 stay within each 32-lane half-wave).
  const float k0 = __expf(acc0 * cneg);
  const float k1 = __expf(acc1 * cneg);
  const float k2 = __expf(acc2 * cneg);
  const float k3 = __expf(acc3 * cneg);

  float mx = fmaxf(fmaxf(k0, k1), fmaxf(k2, k3));
#pragma unroll
  for (int off = 16; off >= 1; off >>= 1) mx = fmaxf(mx, __shfl_xor(mx, off, 64));
  const float e0 = __expf(k0 - mx);
  const float e1 = __expf(k1 - mx);
  const float e2 = __expf(k2 - mx);
  const float e3 = __expf(k3 - mx);
  float ssum = e0 + e1 + e2 + e3;
#pragma unroll
  for (int off = 16; off >= 1; off >>= 1) ssum += __shfl_xor(ssum, off, 64);
  const float r = 1.0f / ssum;

  *(float4*)(out + (size_t)(n * RR + i0 + ty) * RR + j0) =
      make_float4(e0 * r, e1 * r, e2 * r, e3 * r);
}

extern "C" void kernel_launch(void* const* d_in, const int* in_sizes, int n_in,
                              void* d_out, int out_size, void* d_ws, size_t ws_size,
                              hipStream_t stream) {
  const float* x1 = (const float*)d_in[0];
  const float* x2 = (const float*)d_in[1];
  const float* sigma = (const float*)d_in[2];
  const float* mean = (const float*)d_in[3];
  float* out = (float*)d_out;
  (void)d_ws; (void)ws_size;  // deliberately unused: keep the 268 MB ws poison off our path

  gauss_fused<<<dim3(NB * 16), dim3(256), 0, stream>>>(x1, x2, sigma, mean, out);
}